// Round 2
// baseline (1734.715 us; speedup 1.0000x reference)
//
#include <hip/hip_runtime.h>

#define KNN 32
#define BLOCK 256

// ws layout (doubles): [0]=sum_y [1]=sum_y2 [2]=sum_m [3]=sum_m2 [4]=w_sum [5]=num_y [6]=num_m

__global__ __launch_bounds__(BLOCK) void sums_kernel(const float* __restrict__ y,
                                                     const float* __restrict__ m,
                                                     double* __restrict__ ws, int N) {
  int tid = threadIdx.x;
  double sy = 0.0, sy2 = 0.0, sm = 0.0, sm2 = 0.0;
  for (int j = tid; j < N; j += BLOCK) {
    double yv = (double)y[j], mv = (double)m[j];
    sy += yv; sy2 += yv * yv; sm += mv; sm2 += mv * mv;
  }
  for (int off = 32; off > 0; off >>= 1) {
    sy  += __shfl_down(sy, off, 64);
    sy2 += __shfl_down(sy2, off, 64);
    sm  += __shfl_down(sm, off, 64);
    sm2 += __shfl_down(sm2, off, 64);
  }
  __shared__ double red[BLOCK / 64][4];
  int wid = tid >> 6;
  if ((tid & 63) == 0) { red[wid][0] = sy; red[wid][1] = sy2; red[wid][2] = sm; red[wid][3] = sm2; }
  __syncthreads();
  if (tid == 0) {
    double a = 0, b = 0, c = 0, d = 0;
    for (int w = 0; w < BLOCK / 64; ++w) { a += red[w][0]; b += red[w][1]; c += red[w][2]; d += red[w][3]; }
    ws[0] = a; ws[1] = b; ws[2] = c; ws[3] = d;
  }
}

__device__ inline unsigned long long shfl_down_u64(unsigned long long v, int off) {
  unsigned lo = (unsigned)(v & 0xffffffffull);
  unsigned hi = (unsigned)(v >> 32);
  lo = __shfl_down(lo, off, 64);
  hi = __shfl_down(hi, off, 64);
  return (((unsigned long long)hi) << 32) | (unsigned long long)lo;
}

__global__ __launch_bounds__(BLOCK) void knn_moran_kernel(const float* __restrict__ x,
                                                          const float* __restrict__ y,
                                                          const float* __restrict__ m,
                                                          double* __restrict__ ws, int N) {
  __shared__ float s_dist[12288];
  __shared__ unsigned long long s_red[BLOCK / 64];
  __shared__ float s_kd[KNN];
  __shared__ int s_ki[KNN];

  const int i = blockIdx.x;
  const int tid = threadIdx.x;

  const float xi0 = x[i * 4 + 0];
  const float xi1 = x[i * 4 + 1];
  const float sqi = xi0 * xi0 + xi1 * xi1;

  // distances row i -> all j, same formula as reference: sqi + sqj - 2*dot
  for (int j = tid; j < N; j += BLOCK) {
    float xj0 = x[j * 4 + 0];
    float xj1 = x[j * 4 + 1];
    float sqj = xj0 * xj0 + xj1 * xj1;
    float dot = xi0 * xj0 + xi1 * xj1;
    float d2 = sqi + sqj - 2.0f * dot;
    d2 = fmaxf(d2, 1e-30f);
    s_dist[j] = sqrtf(d2);
  }
  __syncthreads();

  // 32 serial argmin extractions (packed key: dist bits high, index low -> ties to smaller idx)
  for (int k = 0; k < KNN; ++k) {
    unsigned long long best = ~0ull;
    for (int j = tid; j < N; j += BLOCK) {
      unsigned long long key =
          (((unsigned long long)__float_as_uint(s_dist[j])) << 32) | (unsigned long long)(unsigned)j;
      if (key < best) best = key;
    }
    for (int off = 32; off > 0; off >>= 1) {
      unsigned long long o = shfl_down_u64(best, off);
      if (o < best) best = o;
    }
    int wid = tid >> 6;
    if ((tid & 63) == 0) s_red[wid] = best;
    __syncthreads();
    if (tid == 0) {
      for (int w = 1; w < BLOCK / 64; ++w)
        if (s_red[w] < best) best = s_red[w];
      int idx = (int)(unsigned)(best & 0xffffffffull);
      float d = __uint_as_float((unsigned)(best >> 32));
      s_kd[k] = d;
      s_ki[k] = idx;
      s_dist[idx] = __uint_as_float(0x7f800000u);  // +inf: remove from further rounds
    }
    __syncthreads();
  }

  // accumulate this row's contributions
  const double mean_y = ws[0] / (double)N;
  const double mean_m = ws[2] / (double)N;

  if (tid < 64) {
    float w = 0.0f, sy = 0.0f, sm = 0.0f;
    if (tid < KNN) {
      int idx = s_ki[tid];
      w = expf(-0.1f * s_kd[tid]);
      sy = w * (float)((double)y[idx] - mean_y);
      sm = w * (float)((double)m[idx] - mean_m);
    }
    for (int off = 32; off > 0; off >>= 1) {
      w  += __shfl_down(w, off, 64);
      sy += __shfl_down(sy, off, 64);
      sm += __shfl_down(sm, off, 64);
    }
    if (tid == 0) {
      float devyi = (float)((double)y[i] - mean_y);
      float devmi = (float)((double)m[i] - mean_m);
      atomicAdd(&ws[4], (double)w);
      atomicAdd(&ws[5], (double)(devyi * sy));
      atomicAdd(&ws[6], (double)(devmi * sm));
    }
  }
}

__global__ void finalize_kernel(const double* __restrict__ ws, float* __restrict__ out, int N) {
  double sum_y = ws[0], sum_y2 = ws[1], sum_m = ws[2], sum_m2 = ws[3];
  double den_y = sum_y2 - sum_y * sum_y / (double)N;
  double den_m = sum_m2 - sum_m * sum_m / (double)N;
  double scale = (double)N / ws[4];
  out[0] = (float)(scale * ws[5] / den_y);
  out[1] = (float)(scale * ws[6] / den_m);
}

extern "C" void kernel_launch(void* const* d_in, const int* in_sizes, int n_in,
                              void* d_out, int out_size, void* d_ws, size_t ws_size,
                              hipStream_t stream) {
  const float* x  = (const float*)d_in[0];  // (1, N, 4)
  const float* y  = (const float*)d_in[1];  // (1, N, 1)
  const float* mu = (const float*)d_in[2];  // (1, N, 1)
  float* out = (float*)d_out;
  int N = in_sizes[1];  // 12288
  double* ws = (double*)d_ws;

  hipMemsetAsync(d_ws, 0, 7 * sizeof(double), stream);
  sums_kernel<<<1, BLOCK, 0, stream>>>(y, mu, ws, N);
  knn_moran_kernel<<<N, BLOCK, 0, stream>>>(x, y, mu, ws, N);
  finalize_kernel<<<1, 1, 0, stream>>>(ws, out, N);
}

// Round 3
// 500.132 us; speedup vs baseline: 3.4685x; 3.4685x over previous
//
#include <hip/hip_runtime.h>

#define KNN 32
#define BLOCK 256
#define NBINS 1024
#define CAP 2048

// ws layout (doubles): [0]=sum_y [1]=sum_y2 [2]=sum_m [3]=sum_m2 [4]=w_sum [5]=num_y [6]=num_m

__global__ __launch_bounds__(BLOCK) void sums_kernel(const float* __restrict__ y,
                                                     const float* __restrict__ m,
                                                     double* __restrict__ ws, int N) {
  int tid = threadIdx.x;
  double sy = 0.0, sy2 = 0.0, sm = 0.0, sm2 = 0.0;
  for (int j = tid; j < N; j += BLOCK) {
    double yv = (double)y[j], mv = (double)m[j];
    sy += yv; sy2 += yv * yv; sm += mv; sm2 += mv * mv;
  }
  for (int off = 32; off > 0; off >>= 1) {
    sy  += __shfl_down(sy, off, 64);
    sy2 += __shfl_down(sy2, off, 64);
    sm  += __shfl_down(sm, off, 64);
    sm2 += __shfl_down(sm2, off, 64);
  }
  __shared__ double red[BLOCK / 64][4];
  int wid = tid >> 6;
  if ((tid & 63) == 0) { red[wid][0] = sy; red[wid][1] = sy2; red[wid][2] = sm; red[wid][3] = sm2; }
  __syncthreads();
  if (tid == 0) {
    double a = 0, b = 0, c = 0, d = 0;
    for (int w = 0; w < BLOCK / 64; ++w) { a += red[w][0]; b += red[w][1]; c += red[w][2]; d += red[w][3]; }
    ws[0] = a; ws[1] = b; ws[2] = c; ws[3] = d;
  }
}

__global__ __launch_bounds__(BLOCK) void knn_moran_kernel(const float4* __restrict__ x4,
                                                          const float* __restrict__ y,
                                                          const float* __restrict__ m,
                                                          double* __restrict__ ws, int N) {
  __shared__ int s_hist[NBINS];
  __shared__ unsigned long long s_cand[CAP];
  __shared__ int s_count;
  __shared__ int s_T;
  __shared__ int s_wsum[BLOCK / 64];
  __shared__ float s_sel_d[KNN];
  __shared__ int s_sel_i[KNN];

  const int i = blockIdx.x;
  const int tid = threadIdx.x;
  const int lane = tid & 63;
  const int wid = tid >> 6;

  for (int b = tid; b < NBINS; b += BLOCK) s_hist[b] = 0;
  if (tid == 0) s_count = 0;

  const float4 xi = x4[i];
  const float xi0 = xi.x, xi1 = xi.y;
  const float sqi = xi0 * xi0 + xi1 * xi1;
  __syncthreads();

  // ---- pass 1: histogram of distance-bit bins (monotone: dist >= 0) ----
  for (int j = tid; j < N; j += BLOCK) {
    float4 xj = x4[j];
    float sqj = xj.x * xj.x + xj.y * xj.y;
    float dot = xi0 * xj.x + xi1 * xj.y;
    float d2 = sqi + sqj - 2.0f * dot;
    d2 = fmaxf(d2, 1e-30f);
    float dist = sqrtf(d2);
    unsigned b = __float_as_uint(dist) >> 21;  // 0..1023
    atomicAdd(&s_hist[b], 1);
  }
  __syncthreads();

  // ---- find threshold bin T: cum[T-1] < KNN <= cum[T] ----
  {
    int base = tid * 4;
    int c0 = s_hist[base], c1 = s_hist[base + 1], c2 = s_hist[base + 2], c3 = s_hist[base + 3];
    int csum = c0 + c1 + c2 + c3;
    int scan = csum;
    for (int off = 1; off < 64; off <<= 1) {
      int v = __shfl_up(scan, off, 64);
      if (lane >= off) scan += v;
    }
    if (lane == 63) s_wsum[wid] = scan;
    __syncthreads();
    int woff = 0;
    for (int w = 0; w < wid; ++w) woff += s_wsum[w];
    int excl = woff + scan - csum;  // exclusive prefix at chunk start
    if (excl < KNN && excl + csum >= KNN) {  // unique crossing chunk
      int run = excl;
      int cc[4] = {c0, c1, c2, c3};
      for (int q = 0; q < 4; ++q) {
        if (run < KNN && run + cc[q] >= KNN) { s_T = base + q; break; }
        run += cc[q];
      }
    }
  }
  __syncthreads();
  const unsigned T = (unsigned)s_T;

  // ---- pass 2: collect candidates (bin <= T) as packed keys ----
  for (int j = tid; j < N; j += BLOCK) {
    float4 xj = x4[j];
    float sqj = xj.x * xj.x + xj.y * xj.y;
    float dot = xi0 * xj.x + xi1 * xj.y;
    float d2 = sqi + sqj - 2.0f * dot;
    d2 = fmaxf(d2, 1e-30f);
    float dist = sqrtf(d2);
    unsigned bits = __float_as_uint(dist);
    if ((bits >> 21) <= T) {
      int pos = atomicAdd(&s_count, 1);
      if (pos < CAP)
        s_cand[pos] = (((unsigned long long)bits) << 32) | (unsigned long long)(unsigned)j;
    }
  }
  __syncthreads();
  int C = s_count;
  if (C > CAP) C = CAP;

  // ---- exact rank selection of the 32 smallest keys (ties -> smaller idx) ----
  for (int c = tid; c < C; c += BLOCK) {
    unsigned long long mine = s_cand[c];
    int rank = 0;
    for (int q = 0; q < C; ++q) rank += (s_cand[q] < mine) ? 1 : 0;
    if (rank < KNN) {
      s_sel_d[rank] = __uint_as_float((unsigned)(mine >> 32));
      s_sel_i[rank] = (int)(unsigned)(mine & 0xffffffffull);
    }
  }
  __syncthreads();

  // ---- accumulate this row's contributions ----
  const double mean_y = ws[0] / (double)N;
  const double mean_m = ws[2] / (double)N;

  if (tid < 64) {
    float w = 0.0f, sy = 0.0f, sm = 0.0f;
    if (tid < KNN) {
      int idx = s_sel_i[tid];
      w = expf(-0.1f * s_sel_d[tid]);
      sy = w * (float)((double)y[idx] - mean_y);
      sm = w * (float)((double)m[idx] - mean_m);
    }
    for (int off = 32; off > 0; off >>= 1) {
      w  += __shfl_down(w, off, 64);
      sy += __shfl_down(sy, off, 64);
      sm += __shfl_down(sm, off, 64);
    }
    if (tid == 0) {
      float devyi = (float)((double)y[i] - mean_y);
      float devmi = (float)((double)m[i] - mean_m);
      atomicAdd(&ws[4], (double)w);
      atomicAdd(&ws[5], (double)(devyi * sy));
      atomicAdd(&ws[6], (double)(devmi * sm));
    }
  }
}

__global__ void finalize_kernel(const double* __restrict__ ws, float* __restrict__ out, int N) {
  double sum_y = ws[0], sum_y2 = ws[1], sum_m = ws[2], sum_m2 = ws[3];
  double den_y = sum_y2 - sum_y * sum_y / (double)N;
  double den_m = sum_m2 - sum_m * sum_m / (double)N;
  double scale = (double)N / ws[4];
  out[0] = (float)(scale * ws[5] / den_y);
  out[1] = (float)(scale * ws[6] / den_m);
}

extern "C" void kernel_launch(void* const* d_in, const int* in_sizes, int n_in,
                              void* d_out, int out_size, void* d_ws, size_t ws_size,
                              hipStream_t stream) {
  const float4* x4 = (const float4*)d_in[0];  // (1, N, 4)
  const float* y   = (const float*)d_in[1];   // (1, N, 1)
  const float* mu  = (const float*)d_in[2];   // (1, N, 1)
  float* out = (float*)d_out;
  int N = in_sizes[1];  // 12288
  double* ws = (double*)d_ws;

  hipMemsetAsync(d_ws, 0, 7 * sizeof(double), stream);
  sums_kernel<<<1, BLOCK, 0, stream>>>(y, mu, ws, N);
  knn_moran_kernel<<<N, BLOCK, 0, stream>>>(x4, y, mu, ws, N);
  finalize_kernel<<<1, 1, 0, stream>>>(ws, out, N);
}